// Round 1
// baseline (600.753 us; speedup 1.0000x reference)
//
#include <hip/hip_runtime.h>
#include <hip/hip_bf16.h>
#include <math.h>

// Work entirely in rolled token coordinates (roll(-SH) on inputs == inverse of
// roll(+SH) on output, same permutation for all modalities, downstream ops are
// pointwise per token). M = B*T*L = 4096 rolled tokens, windows = contiguous
// 512-row blocks. Only the final store un-rolls.

typedef __bf16 bf16x8 __attribute__((ext_vector_type(8)));
typedef float f32x4 __attribute__((ext_vector_type(4)));

#define MTOK 4096
#define DMODEL 1024
#define ELEM4M 4194304ull   // 4096*1024
#define ELEM1M 1048576ull   // 1024*1024

__device__ __forceinline__ float b2f(short s) {
    unsigned u = ((unsigned)(unsigned short)s) << 16;
    float f; __builtin_memcpy(&f, &u, 4); return f;
}
__device__ __forceinline__ short f2b(float f) {
    unsigned u; __builtin_memcpy(&u, &f, 4);
    u = (u + 0x7fffu + ((u >> 16) & 1u)) >> 16;
    return (short)u;
}

// ---------------- cast + roll inputs: rolled[b,t',l,d] = bf16(x[b,(t'+4)%32,l,d])
__global__ __launch_bounds__(256) void cast_roll_k(
    const float* __restrict__ a, const float* __restrict__ v,
    const float* __restrict__ im, short* __restrict__ dst)
{
    int z = blockIdx.y;
    const float* src = (z == 0) ? a : ((z == 1) ? v : im);
    int i = (blockIdx.x * 256 + threadIdx.x) * 4;   // elem idx in 4M
    int row = i >> 10, d = i & 1023;
    int b = row >> 11, tp = (row >> 6) & 31, l = row & 63;
    int srow = (b << 11) + (((tp + 4) & 31) << 6) + l;
    float4 val = *(const float4*)(src + (size_t)srow * 1024 + d);
    short4 o;
    o.x = f2b(val.x); o.y = f2b(val.y); o.z = f2b(val.z); o.w = f2b(val.w);
    *(short4*)(dst + (size_t)z * ELEM4M + i) = o;
}

// ---------------- weight transpose: dst[n][k] = bf16(src[k][n])
__device__ __forceinline__ void transpose_body(const float* __restrict__ src,
                                               short* __restrict__ dst, int K, int N)
{
    __shared__ float tile[32][33];
    int x = blockIdx.x * 32 + threadIdx.x;   // n
    int y0 = blockIdx.y * 32;                // k base
#pragma unroll
    for (int i = 0; i < 32; i += 8)
        tile[threadIdx.y + i][threadIdx.x] = src[(size_t)(y0 + threadIdx.y + i) * N + x];
    __syncthreads();
    int x2 = y0 + threadIdx.x;               // k
    int y2 = blockIdx.x * 32 + threadIdx.y;  // n
#pragma unroll
    for (int i = 0; i < 32; i += 8)
        dst[(size_t)(y2 + i) * K + x2] = f2b(tile[threadIdx.x][threadIdx.y + i]);
}

__global__ void transpose_qkvp_k(const float* Wq, const float* Wk, const float* Wv,
                                 const float* Wp, short* dst)
{
    int z = blockIdx.z;             // 0..11 : Wq0..2, Wk0..2, Wv0..2, Wp0..2
    int g = z / 3, j = z - g * 3;
    const float* s4[4] = {Wq, Wk, Wv, Wp};
    transpose_body(s4[g] + (size_t)j * ELEM1M, dst + (size_t)z * ELEM1M, 1024, 1024);
}

__global__ void transpose_wg1_k(const float* Wg1, short* dst)
{
    transpose_body(Wg1, dst, 3072, 2048);   // src [3072][2048] -> dst [2048][3072]
}

// ---------------- bf16 GEMM: C[M,N] = act(A[M,K] @ W[K,N] + bias) (+res), W given as Wt[N][K]
// 128x128 tile, 4 waves each 64x64 (4x4 of 16x16x32 MFMA). Verified layouts:
// A-frag: A[m=lane&15][k=quad*8+j]; B-frag: B[k=quad*8+j][n=lane&15] (read from Wt[n][k]);
// C/D: col=lane&15, row=quad*4+reg.
template<bool GELU, bool RES>
__device__ __forceinline__ void gemm_core(
    const short* __restrict__ A, const short* __restrict__ Wt,
    const float* __restrict__ bias, const short* __restrict__ Res,
    short* __restrict__ C, int ldc, int colOff, int Ksz)
{
    __shared__ __align__(16) short As[128 * 40];   // +8 pad: 2-way LDS aliasing only
    __shared__ __align__(16) short Bs[128 * 40];
    const int tid = threadIdx.x;
    const int wave = tid >> 6, lane = tid & 63, quad = lane >> 4, l15 = lane & 15;
    const int wm = (wave & 1) * 64, wn = (wave >> 1) * 64;
    const int row0 = blockIdx.x * 128, col0 = blockIdx.y * 128;

    f32x4 acc[4][4];
#pragma unroll
    for (int i = 0; i < 4; i++)
#pragma unroll
        for (int j = 0; j < 4; j++) acc[i][j] = f32x4{0.f, 0.f, 0.f, 0.f};

    for (int k0 = 0; k0 < Ksz; k0 += 32) {
#pragma unroll
        for (int c = tid; c < 512; c += 256) {
            int r = c >> 2, seg = c & 3;
            *(uint4*)(As + r * 40 + seg * 8) =
                *(const uint4*)(A + (size_t)(row0 + r) * Ksz + k0 + seg * 8);
            *(uint4*)(Bs + r * 40 + seg * 8) =
                *(const uint4*)(Wt + (size_t)(col0 + r) * Ksz + k0 + seg * 8);
        }
        __syncthreads();
        bf16x8 af[4], bfr[4];
#pragma unroll
        for (int mi = 0; mi < 4; mi++)
            af[mi] = *(const bf16x8*)(As + (wm + mi * 16 + l15) * 40 + quad * 8);
#pragma unroll
        for (int ni = 0; ni < 4; ni++)
            bfr[ni] = *(const bf16x8*)(Bs + (wn + ni * 16 + l15) * 40 + quad * 8);
#pragma unroll
        for (int mi = 0; mi < 4; mi++)
#pragma unroll
            for (int ni = 0; ni < 4; ni++)
                acc[mi][ni] = __builtin_amdgcn_mfma_f32_16x16x32_bf16(
                    af[mi], bfr[ni], acc[mi][ni], 0, 0, 0);
        __syncthreads();
    }

#pragma unroll
    for (int mi = 0; mi < 4; mi++) {
#pragma unroll
        for (int ni = 0; ni < 4; ni++) {
            int col = col0 + wn + ni * 16 + l15;
            float bv = bias[col];
#pragma unroll
            for (int r = 0; r < 4; r++) {
                int row = row0 + wm + mi * 16 + quad * 4 + r;
                float v = acc[mi][ni][r] + bv;
                if (GELU) v = 0.5f * v * (1.0f + erff(v * 0.70710678118f));
                if (RES)  v += b2f(Res[(size_t)row * 1024 + col]);
                C[(size_t)row * ldc + colOff + col] = f2b(v);
            }
        }
    }
}

__global__ __launch_bounds__(256) void gemm_qkv_k(
    const short* r0, const short* r1, const short* r2,
    const short* Wt, const float* bq, const float* bk, const float* bv, short* qkv)
{
    int z = blockIdx.z;           // 0..8 : Q0..2, K0..2, V0..2
    int g = z / 3, j = z - g * 3;
    const short* rolled[3] = {r0, r1, r2};
    const int kvmap[3] = {1, 0, 1};   // kv modality: video, audio, video
    const short* A = (g == 0) ? rolled[j] : rolled[kvmap[j]];
    const float* bias = ((g == 0) ? bq : ((g == 1) ? bk : bv)) + j * 1024;
    gemm_core<false, false>(A, Wt + (size_t)z * ELEM1M, bias, nullptr,
                            qkv + (size_t)z * ELEM4M, 1024, 0, 1024);
}

__global__ __launch_bounds__(256) void gemm_out_k(
    const short* attnO, const short* Wt9, const float* bp,
    const short* r0, const short* r1, const short* r2, short* fcat)
{
    int j = blockIdx.z;
    const short* rolled[3] = {r0, r1, r2};
    gemm_core<false, true>(attnO + (size_t)j * ELEM4M, Wt9 + (size_t)j * ELEM1M,
                           bp + j * 1024, rolled[j], fcat, 3072, j * 1024, 1024);
}

__global__ __launch_bounds__(256) void gemm_gate_k(
    const short* fcat, const short* Wg1t, const float* bg1, short* g1)
{
    gemm_core<true, false>(fcat, Wg1t, bg1, nullptr, g1, 2048, 0, 3072);
}

// ---------------- RMS norm over head_dim (in place on Q and K); Q also gets *HD^-0.5
__global__ __launch_bounds__(256) void rms_k(short* qkv, const float* qn, const float* kn)
{
    int z = blockIdx.y;           // 0..5 : Q0..2, K0..2
    int g = z / 3, j = z - g * 3;
    short* buf = qkv + (size_t)(g * 3 + j) * ELEM4M;
    const float* w = (g ? kn : qn) + j * 64;
    float scale = g ? 1.0f : 0.125f;
    int row = blockIdx.x, t = threadIdx.x;
    int h = t >> 4, hd0 = (t & 15) * 4;
    short* p = buf + (size_t)row * 1024 + h * 64 + hd0;
    short4 s4 = *(short4*)p;
    float x0 = b2f(s4.x), x1 = b2f(s4.y), x2 = b2f(s4.z), x3 = b2f(s4.w);
    float ss = x0 * x0 + x1 * x1 + x2 * x2 + x3 * x3;
    ss += __shfl_xor(ss, 1); ss += __shfl_xor(ss, 2);
    ss += __shfl_xor(ss, 4); ss += __shfl_xor(ss, 8);
    float sc = rsqrtf(ss * (1.0f / 64.0f) + 1e-6f) * scale;
    s4.x = f2b(x0 * sc * w[hd0 + 0]);
    s4.y = f2b(x1 * sc * w[hd0 + 1]);
    s4.z = f2b(x2 * sc * w[hd0 + 2]);
    s4.w = f2b(x3 * sc * w[hd0 + 3]);
    *(short4*)p = s4;
}

// ---------------- flash-style windowed attention: one block per (pair, win, head, 64 q-rows)
__global__ __launch_bounds__(256) void attn_k(
    const short* __restrict__ qkv, const float* __restrict__ rpb, short* __restrict__ attnO)
{
    const int qt = blockIdx.x;           // q temporal pos in window (0..7)
    const int win = blockIdx.y >> 4, h = blockIdx.y & 15;
    const int j = blockIdx.z;
    const int tid = threadIdx.x, wave = tid >> 6, lane = tid & 63;
    const int quad = lane >> 4, l15 = lane & 15;

    const short* Qp = qkv + (size_t)j * ELEM4M + (size_t)(win * 512 + qt * 64) * 1024 + h * 64;
    const short* Kp = qkv + (size_t)(3 + j) * ELEM4M + (size_t)(win * 512) * 1024 + h * 64;
    const short* Vp = qkv + (size_t)(6 + j) * ELEM4M + (size_t)(win * 512) * 1024 + h * 64;

    __shared__ __align__(16) short Qs[64 * 72];
    __shared__ __align__(16) short Ks[64 * 72];
    __shared__ __align__(16) short Vt[64 * 72];   // V transposed: [hd][key]
    __shared__ __align__(16) short Ps[4][16 * 72]; // per-wave P tile (q-local x key)

    for (int c = tid; c < 512; c += 256) {
        int r = c >> 3, seg = c & 7;
        *(uint4*)(Qs + r * 72 + seg * 8) = *(const uint4*)(Qp + (size_t)r * 1024 + seg * 8);
    }
    __syncthreads();

    bf16x8 qa[2];
    qa[0] = *(const bf16x8*)(Qs + (wave * 16 + l15) * 72 + quad * 8);
    qa[1] = *(const bf16x8*)(Qs + (wave * 16 + l15) * 72 + 32 + quad * 8);

    f32x4 oacc[4];
#pragma unroll
    for (int ni = 0; ni < 4; ni++) oacc[ni] = f32x4{0.f, 0.f, 0.f, 0.f};
    float m_i[4], l_i[4];
#pragma unroll
    for (int r = 0; r < 4; r++) { m_i[r] = -1e30f; l_i[r] = 0.f; }

    const float* rpbj = rpb + j * 240;   // [15][16]
    short* Pw = Ps[wave];

    for (int kt = 0; kt < 8; kt++) {
        for (int c = tid; c < 512; c += 256) {
            int r = c >> 3, seg = c & 7;
            *(uint4*)(Ks + r * 72 + seg * 8) =
                *(const uint4*)(Kp + (size_t)(kt * 64 + r) * 1024 + seg * 8);
            union { uint4 u; short s[8]; } vv;
            vv.u = *(const uint4*)(Vp + (size_t)(kt * 64 + r) * 1024 + seg * 8);
#pragma unroll
            for (int i = 0; i < 8; i++) Vt[(seg * 8 + i) * 72 + r] = vv.s[i];
        }
        __syncthreads();

        f32x4 sacc[4];
#pragma unroll
        for (int ni = 0; ni < 4; ni++) sacc[ni] = f32x4{0.f, 0.f, 0.f, 0.f};
#pragma unroll
        for (int ks = 0; ks < 2; ks++)
#pragma unroll
            for (int ni = 0; ni < 4; ni++) {
                bf16x8 kb = *(const bf16x8*)(Ks + (ni * 16 + l15) * 72 + ks * 32 + quad * 8);
                sacc[ni] = __builtin_amdgcn_mfma_f32_16x16x32_bf16(qa[ks], kb, sacc[ni], 0, 0, 0);
            }

        float bv = rpbj[(qt - kt + 7) * 16 + h];   // scalar bias for whole tile
#pragma unroll
        for (int r = 0; r < 4; r++) {
            float mx = -1e30f;
#pragma unroll
            for (int ni = 0; ni < 4; ni++) mx = fmaxf(mx, sacc[ni][r]);
            mx = fmaxf(mx, __shfl_xor(mx, 1)); mx = fmaxf(mx, __shfl_xor(mx, 2));
            mx = fmaxf(mx, __shfl_xor(mx, 4)); mx = fmaxf(mx, __shfl_xor(mx, 8));
            mx += bv;
            float mnew = fmaxf(m_i[r], mx);
            float alpha = __expf(m_i[r] - mnew);
            float rsum = 0.f;
#pragma unroll
            for (int ni = 0; ni < 4; ni++) {
                float p = __expf(sacc[ni][r] + bv - mnew);
                rsum += p;
                Pw[(quad * 4 + r) * 72 + ni * 16 + l15] = f2b(p);
            }
            rsum += __shfl_xor(rsum, 1); rsum += __shfl_xor(rsum, 2);
            rsum += __shfl_xor(rsum, 4); rsum += __shfl_xor(rsum, 8);
            l_i[r] = l_i[r] * alpha + rsum;
            m_i[r] = mnew;
#pragma unroll
            for (int ni = 0; ni < 4; ni++) oacc[ni][r] *= alpha;
        }

        // PV: Ps written+read by same wave only -> no barrier needed before this
#pragma unroll
        for (int ks = 0; ks < 2; ks++) {
            bf16x8 pa = *(const bf16x8*)(Pw + l15 * 72 + ks * 32 + quad * 8);
#pragma unroll
            for (int ni = 0; ni < 4; ni++) {
                bf16x8 vb = *(const bf16x8*)(Vt + (ni * 16 + l15) * 72 + ks * 32 + quad * 8);
                oacc[ni] = __builtin_amdgcn_mfma_f32_16x16x32_bf16(pa, vb, oacc[ni], 0, 0, 0);
            }
        }
        __syncthreads();   // protect Ks/Vt before next stage
    }

    short* Op = attnO + (size_t)j * ELEM4M;
#pragma unroll
    for (int ni = 0; ni < 4; ni++)
#pragma unroll
        for (int r = 0; r < 4; r++) {
            int row = win * 512 + qt * 64 + wave * 16 + quad * 4 + r;
            int col = h * 64 + ni * 16 + l15;
            Op[(size_t)row * 1024 + col] = f2b(oacc[ni][r] / l_i[r]);
        }
}

// ---------------- gate dot (g1 @ Wg2 + bg2), softmax-3, fuse, un-roll store
__global__ __launch_bounds__(256) void fuse_k(
    const short* __restrict__ g1, const short* __restrict__ fcat,
    const float* __restrict__ Wg2, const float* __restrict__ bg2,
    float* __restrict__ out)
{
    int row = blockIdx.x, tid = threadIdx.x;
    const short* gp = g1 + (size_t)row * 2048;
    float a0 = 0.f, a1 = 0.f, a2 = 0.f;
    for (int k = tid; k < 2048; k += 256) {
        float gv = b2f(gp[k]);
        a0 += gv * Wg2[k * 3 + 0];
        a1 += gv * Wg2[k * 3 + 1];
        a2 += gv * Wg2[k * 3 + 2];
    }
#pragma unroll
    for (int off = 1; off < 64; off <<= 1) {
        a0 += __shfl_xor(a0, off); a1 += __shfl_xor(a1, off); a2 += __shfl_xor(a2, off);
    }
    __shared__ float part[4][3];
    int wave = tid >> 6, lane = tid & 63;
    if (lane == 0) { part[wave][0] = a0; part[wave][1] = a1; part[wave][2] = a2; }
    __syncthreads();
    float g0 = part[0][0] + part[1][0] + part[2][0] + part[3][0] + bg2[0];
    float gA = part[0][1] + part[1][1] + part[2][1] + part[3][1] + bg2[1];
    float gB = part[0][2] + part[1][2] + part[2][2] + part[3][2] + bg2[2];
    float mx = fmaxf(g0, fmaxf(gA, gB));
    float e0 = __expf(g0 - mx), e1 = __expf(gA - mx), e2 = __expf(gB - mx);
    float inv = 1.0f / (e0 + e1 + e2);
    e0 *= inv; e1 *= inv; e2 *= inv;

    int b = row >> 11, tp = (row >> 6) & 31, l = row & 63;
    size_t orow = (size_t)(b * 32 + ((tp + 4) & 31)) * 64 + l;   // un-roll (+SH)
    const short* f0 = fcat + (size_t)row * 3072;
    float* op = out + orow * 1024;
    for (int c = tid; c < 1024; c += 256)
        op[c] = e0 * b2f(f0[c]) + e1 * b2f(f0[1024 + c]) + e2 * b2f(f0[2048 + c]);
}

extern "C" void kernel_launch(void* const* d_in, const int* in_sizes, int n_in,
                              void* d_out, int out_size, void* d_ws, size_t ws_size,
                              hipStream_t stream)
{
    const float* audio = (const float*)d_in[0];
    const float* video = (const float*)d_in[1];
    const float* image = (const float*)d_in[2];
    const float* Wq = (const float*)d_in[3];
    const float* Wk = (const float*)d_in[4];
    const float* Wv = (const float*)d_in[5];
    const float* Wp = (const float*)d_in[6];
    const float* bq = (const float*)d_in[7];
    const float* bk = (const float*)d_in[8];
    const float* bv = (const float*)d_in[9];
    const float* bp = (const float*)d_in[10];
    const float* qn = (const float*)d_in[11];
    const float* kn = (const float*)d_in[12];
    const float* rpb = (const float*)d_in[13];
    const float* Wg1 = (const float*)d_in[14];
    const float* bg1 = (const float*)d_in[15];
    const float* Wg2 = (const float*)d_in[16];
    const float* bg2 = (const float*)d_in[17];
    float* out = (float*)d_out;

    // workspace layout (shorts). Total = 94,371,840 shorts = 180 MiB.
    short* ws = (short*)d_ws;
    short* rolled = ws;                                  // 3 * 4M
    short* Wt     = rolled + 3 * ELEM4M;                 // 12 * 1M (Wq,Wk,Wv,Wp x3, transposed)
    short* Wg1t   = Wt + 12 * ELEM1M;                    // 6M  [2048][3072]
    short* qkv    = Wg1t + 6 * ELEM1M;                   // 9 * 4M (Q0..2,K0..2,V0..2)
    short* attnO  = qkv + 9 * ELEM4M;                    // 3 * 4M
    short* fcat   = attnO + 3 * ELEM4M;                  // 4096*3072
    short* g1buf  = qkv;                                 // overlay: qkv dead after attn

    cast_roll_k<<<dim3(4096, 3), 256, 0, stream>>>(audio, video, image, rolled);
    transpose_qkvp_k<<<dim3(32, 32, 12), dim3(32, 8), 0, stream>>>(Wq, Wk, Wv, Wp, Wt);
    transpose_wg1_k<<<dim3(64, 96), dim3(32, 8), 0, stream>>>(Wg1, Wg1t);
    gemm_qkv_k<<<dim3(32, 8, 9), 256, 0, stream>>>(
        rolled, rolled + ELEM4M, rolled + 2 * ELEM4M, Wt, bq, bk, bv, qkv);
    rms_k<<<dim3(4096, 6), 256, 0, stream>>>(qkv, qn, kn);
    attn_k<<<dim3(8, 128, 3), 256, 0, stream>>>(qkv, rpb, attnO);
    gemm_out_k<<<dim3(32, 8, 3), 256, 0, stream>>>(
        attnO, Wt + 9 * ELEM1M, bp, rolled, rolled + ELEM4M, rolled + 2 * ELEM4M, fcat);
    gemm_gate_k<<<dim3(32, 16), 256, 0, stream>>>(fcat, Wg1t, bg1, g1buf);
    fuse_k<<<4096, 256, 0, stream>>>(g1buf, fcat, Wg2, bg2, out);
}